// Round 1
// baseline (326.580 us; speedup 1.0000x reference)
//
#include <hip/hip_runtime.h>
#include <math.h>

#define TQ   32768    // total tokens N*H*W
#define HWSZ 16384    // H*W
#define CC   64
#define HH   128
#define WW   128
#define C3   192
#define C4   256
#define KS   7

// ---------------- K1: LN1.  x (N,C,H,W) -> xn channel-major [C][T] ----------------
__global__ __launch_bounds__(256) void k_ln1(const float* __restrict__ x,
        const float* __restrict__ w, const float* __restrict__ b,
        float* __restrict__ xn) {
    int t = blockIdx.x * 256 + threadIdx.x;
    int n = t >> 14, hw = t & (HWSZ - 1);
    const float* xr = x + ((size_t)n << 20) + hw;   // n*C*HW
    float s = 0.f, s2 = 0.f;
#pragma unroll
    for (int c = 0; c < CC; ++c) { float v = xr[c * HWSZ]; s += v; s2 += v * v; }
    float m = s * (1.f / 64.f);
    float var = s2 * (1.f / 64.f) - m * m;
    float r = rsqrtf(var + 1e-5f);
#pragma unroll
    for (int c = 0; c < CC; ++c) {
        float v = xr[c * HWSZ];
        xn[(size_t)c * TQ + t] = (v - m) * r * w[c] + b[c];
    }
}

// ---------------- K2: QKV GEMM. xn [C][T] -> qkv token-major [T][192] ----------------
// out[t,j] = dot(xn[:,t], qkv_w[j,:]) + b[j];  q-part (j<64) scaled by dh^-0.5
__global__ __launch_bounds__(256) void k_qkv(const float* __restrict__ xn,
        const float* __restrict__ qw, const float* __restrict__ qb,
        float* __restrict__ qkv) {
    __shared__ __align__(16) float w_s[C3 * 65];
    __shared__ __align__(16) float x_s[CC * 68];
    __shared__ float b_s[C3];
    int tid = threadIdx.x;
    int t0 = blockIdx.x * 64;
    for (int i = tid; i < C3 * CC; i += 256) {
        int j = i >> 6, k = i & 63;
        w_s[j * 65 + k] = qw[i];
    }
    if (tid < C3) b_s[tid] = qb[tid];
    {
        int tl = tid & 63, kq = tid >> 6;
        for (int p = 0; p < 16; ++p) {
            int k = p * 4 + kq;
            x_s[k * 68 + tl] = xn[(size_t)k * TQ + t0 + tl];
        }
    }
    __syncthreads();
    int jl = tid & 63, tg = tid >> 6;
    float a0[16], a1[16], a2[16];
#pragma unroll
    for (int i = 0; i < 16; ++i) { a0[i] = 0.f; a1[i] = 0.f; a2[i] = 0.f; }
    for (int k = 0; k < CC; ++k) {
        float w0 = w_s[jl * 65 + k];
        float w1 = w_s[(jl + 64) * 65 + k];
        float w2 = w_s[(jl + 128) * 65 + k];
        const float4* xp = (const float4*)&x_s[k * 68 + tg * 16];
#pragma unroll
        for (int q = 0; q < 4; ++q) {
            float4 xv = xp[q];
            a0[q*4+0] += w0 * xv.x; a0[q*4+1] += w0 * xv.y; a0[q*4+2] += w0 * xv.z; a0[q*4+3] += w0 * xv.w;
            a1[q*4+0] += w1 * xv.x; a1[q*4+1] += w1 * xv.y; a1[q*4+2] += w1 * xv.z; a1[q*4+3] += w1 * xv.w;
            a2[q*4+0] += w2 * xv.x; a2[q*4+1] += w2 * xv.y; a2[q*4+2] += w2 * xv.z; a2[q*4+3] += w2 * xv.w;
        }
    }
    const float qscale = 0.17677669529663687f;  // 1/sqrt(32)
    float bq = b_s[jl], bk = b_s[jl + 64], bv = b_s[jl + 128];
#pragma unroll
    for (int i = 0; i < 16; ++i) {
        size_t t = (size_t)(t0 + tg * 16 + i);
        qkv[t * C3 + jl]        = (a0[i] + bq) * qscale;
        qkv[t * C3 + 64 + jl]   = a1[i] + bk;
        qkv[t * C3 + 128 + jl]  = a2[i] + bv;
    }
}

// ---------------- K3: neighborhood attention. qkv [T][192] -> out token-major [T][64] ----------------
// one wave per query (both heads): lane = z*32 + d
__global__ __launch_bounds__(256) void k_attn(const float* __restrict__ qkv,
        const float* __restrict__ rpb, float* __restrict__ out) {
    __shared__ float rpb_s[2 * 13 * 13];
    __shared__ float p_s[4][2][64];
    int tid = threadIdx.x;
    for (int i = tid; i < 338; i += 256) rpb_s[i] = rpb[i];
    __syncthreads();
    int wv = tid >> 6, lane = tid & 63;
    int z = lane >> 5, d = lane & 31;
    int qi = blockIdx.x * 4 + wv;
    int n = qi >> 14, hw = qi & (HWSZ - 1);
    int h = hw >> 7, wc = hw & 127;
    int sh = min(max(h - 3, 0), HH - KS);
    int sw = min(max(wc - 3, 0), WW - KS);
    float qf = qkv[(size_t)qi * C3 + lane];
    int base = n * HWSZ;
    for (int i = 0; i < KS; ++i) {
        int rn = sh + i;
        int relh = h - rn + 6;
        for (int j = 0; j < KS; ++j) {
            int cn = sw + j;
            int tn = base + rn * WW + cn;
            float kv = qkv[(size_t)tn * C3 + 64 + lane];
            float s = qf * kv;
            s += __shfl_xor(s, 16); s += __shfl_xor(s, 8); s += __shfl_xor(s, 4);
            s += __shfl_xor(s, 2);  s += __shfl_xor(s, 1);
            s += rpb_s[(z * 13 + relh) * 13 + (wc - cn + 6)];
            if (d == 0) p_s[wv][z][i * 7 + j] = s;
        }
    }
    __syncthreads();
    // softmax over 49 scores per (wave, head): lanes of each half cooperate
    float s1 = p_s[wv][z][d];
    float s2 = (d < 17) ? p_s[wv][z][32 + d] : -1e30f;
    float mx = fmaxf(s1, s2);
    mx = fmaxf(mx, __shfl_xor(mx, 16)); mx = fmaxf(mx, __shfl_xor(mx, 8));
    mx = fmaxf(mx, __shfl_xor(mx, 4));  mx = fmaxf(mx, __shfl_xor(mx, 2));
    mx = fmaxf(mx, __shfl_xor(mx, 1));
    float e1 = __expf(s1 - mx);
    float e2 = (d < 17) ? __expf(s2 - mx) : 0.f;
    float sm = e1 + e2;
    sm += __shfl_xor(sm, 16); sm += __shfl_xor(sm, 8); sm += __shfl_xor(sm, 4);
    sm += __shfl_xor(sm, 2);  sm += __shfl_xor(sm, 1);
    float inv = 1.f / sm;
    p_s[wv][z][d] = e1 * inv;
    if (d < 17) p_s[wv][z][32 + d] = e2 * inv;
    __syncthreads();
    float acc = 0.f;
    for (int i = 0; i < KS; ++i) {
        int rn = sh + i;
        for (int j = 0; j < KS; ++j) {
            int cn = sw + j;
            int tn = base + rn * WW + cn;
            float vv = qkv[(size_t)tn * C3 + 128 + lane];
            acc += p_s[wv][z][i * 7 + j] * vv;
        }
    }
    out[(size_t)qi * CC + lane] = acc;
}

// ---------------- K4: proj GEMM + residual. attn [T][64] -> x2 [C][T] ----------------
__global__ __launch_bounds__(256) void k_proj(const float* __restrict__ ain,
        const float* __restrict__ pw, const float* __restrict__ pb,
        const float* __restrict__ x, float* __restrict__ x2) {
    __shared__ __align__(16) float wt_s[CC * 68];
    __shared__ float x_s[CC * 65];
    int tid = threadIdx.x;
    int t0 = blockIdx.x * 64;
    for (int i = tid; i < CC * CC; i += 256) {
        int j = i >> 6, k = i & 63;
        wt_s[k * 68 + j] = pw[i];
    }
    for (int i = tid; i < 64 * 64; i += 256) {
        int tt = i >> 6, c = i & 63;
        x_s[c * 65 + tt] = ain[(size_t)(t0 + tt) * CC + c];
    }
    __syncthreads();
    int tl = tid & 63, jg = tid >> 6;
    float acc[16];
#pragma unroll
    for (int i = 0; i < 16; ++i) acc[i] = 0.f;
    for (int k = 0; k < CC; ++k) {
        float xv = x_s[k * 65 + tl];
        const float4* wp = (const float4*)&wt_s[k * 68 + jg * 16];
#pragma unroll
        for (int q = 0; q < 4; ++q) {
            float4 w4 = wp[q];
            acc[q*4+0] += xv * w4.x; acc[q*4+1] += xv * w4.y;
            acc[q*4+2] += xv * w4.z; acc[q*4+3] += xv * w4.w;
        }
    }
    int t = t0 + tl;
    int n = t >> 14, hw = t & (HWSZ - 1);
#pragma unroll
    for (int jj = 0; jj < 16; ++jj) {
        int j = jg * 16 + jj;
        float resid = x[((size_t)(n * CC + j) << 14) + hw];
        x2[(size_t)j * TQ + t] = acc[jj] + pb[j] + resid;
    }
}

// ---------------- K5: LN2. x2 [C][T] -> xout [C][T] ----------------
__global__ __launch_bounds__(256) void k_ln2(const float* __restrict__ xin,
        const float* __restrict__ w, const float* __restrict__ b,
        float* __restrict__ xout) {
    int t = blockIdx.x * 256 + threadIdx.x;
    float s = 0.f, s2 = 0.f;
#pragma unroll
    for (int c = 0; c < CC; ++c) { float v = xin[(size_t)c * TQ + t]; s += v; s2 += v * v; }
    float m = s * (1.f / 64.f);
    float var = s2 * (1.f / 64.f) - m * m;
    float r = rsqrtf(var + 1e-5f);
#pragma unroll
    for (int c = 0; c < CC; ++c) {
        float v = xin[(size_t)c * TQ + t];
        xout[(size_t)c * TQ + t] = (v - m) * r * w[c] + b[c];
    }
}

// ---------------- K6: FC1 + exact GELU. xln2 [C][T] -> h [C4][T] ----------------
__global__ __launch_bounds__(256) void k_fc1(const float* __restrict__ xin,
        const float* __restrict__ fw, const float* __restrict__ fb,
        float* __restrict__ hbuf) {
    __shared__ __align__(16) float wt_s[CC * 132];
    __shared__ float x_s[CC * 65];
    int tid = threadIdx.x;
    int jb = (blockIdx.x & 1) * 128;
    int t0 = (blockIdx.x >> 1) * 64;
    for (int i = tid; i < 128 * 64; i += 256) {
        int j = i >> 6, k = i & 63;
        wt_s[k * 132 + j] = fw[(size_t)(jb + j) * CC + k];
    }
    int tl = tid & 63, kq = tid >> 6;
    for (int p = 0; p < 16; ++p) {
        int k = p * 4 + kq;
        x_s[k * 65 + tl] = xin[(size_t)k * TQ + t0 + tl];
    }
    __syncthreads();
    int jg = tid >> 6;
    float acc[32];
#pragma unroll
    for (int i = 0; i < 32; ++i) acc[i] = 0.f;
    for (int k = 0; k < CC; ++k) {
        float xv = x_s[k * 65 + tl];
        const float4* wp = (const float4*)&wt_s[k * 132 + jg * 32];
#pragma unroll
        for (int q = 0; q < 8; ++q) {
            float4 w4 = wp[q];
            acc[q*4+0] += xv * w4.x; acc[q*4+1] += xv * w4.y;
            acc[q*4+2] += xv * w4.z; acc[q*4+3] += xv * w4.w;
        }
    }
    int t = t0 + tl;
#pragma unroll
    for (int jj = 0; jj < 32; ++jj) {
        int j = jb + jg * 32 + jj;
        float val = acc[jj] + fb[j];
        float g = 0.5f * val * (1.f + erff(val * 0.70710678118654752f));
        hbuf[(size_t)j * TQ + t] = g;
    }
}

// ---------------- K7: FC2 + residual + NCHW output. h [C4][T], x2 [C][T] -> out (N,C,H,W) ----------------
__global__ __launch_bounds__(256) void k_fc2(const float* __restrict__ hbuf,
        const float* __restrict__ fw, const float* __restrict__ fb,
        const float* __restrict__ x2, float* __restrict__ out) {
    __shared__ __align__(16) float wt_s[CC * 68];
    __shared__ float x_s[CC * 65];
    int tid = threadIdx.x;
    int t0 = blockIdx.x * 64;
    int tl = tid & 63, jg = tid >> 6;
    float acc[16];
#pragma unroll
    for (int i = 0; i < 16; ++i) acc[i] = 0.f;
    for (int kb = 0; kb < 4; ++kb) {
        __syncthreads();
        for (int i = tid; i < 64 * 64; i += 256) {
            int j = i >> 6, kl = i & 63;
            wt_s[kl * 68 + j] = fw[(size_t)j * C4 + kb * 64 + kl];
        }
        for (int p = 0; p < 16; ++p) {
            int kl = p * 4 + (tid >> 6);
            x_s[kl * 65 + tl] = hbuf[(size_t)(kb * 64 + kl) * TQ + t0 + tl];
        }
        __syncthreads();
        for (int kl = 0; kl < 64; ++kl) {
            float xv = x_s[kl * 65 + tl];
            const float4* wp = (const float4*)&wt_s[kl * 68 + jg * 16];
#pragma unroll
            for (int q = 0; q < 4; ++q) {
                float4 w4 = wp[q];
                acc[q*4+0] += xv * w4.x; acc[q*4+1] += xv * w4.y;
                acc[q*4+2] += xv * w4.z; acc[q*4+3] += xv * w4.w;
            }
        }
    }
    int t = t0 + tl;
    int n = t >> 14, hw = t & (HWSZ - 1);
#pragma unroll
    for (int jj = 0; jj < 16; ++jj) {
        int j = jg * 16 + jj;
        float val = acc[jj] + fb[j] + x2[(size_t)j * TQ + t];
        out[((size_t)(n * CC + j) << 14) + hw] = val;
    }
}

extern "C" void kernel_launch(void* const* d_in, const int* in_sizes, int n_in,
                              void* d_out, int out_size, void* d_ws, size_t ws_size,
                              hipStream_t stream) {
    const float* x      = (const float*)d_in[0];
    const float* qkv_w  = (const float*)d_in[1];
    const float* qkv_b  = (const float*)d_in[2];
    const float* proj_w = (const float*)d_in[3];
    const float* proj_b = (const float*)d_in[4];
    const float* rpb    = (const float*)d_in[5];
    const float* ln1_w  = (const float*)d_in[6];
    const float* ln1_b  = (const float*)d_in[7];
    const float* ln2_w  = (const float*)d_in[8];
    const float* ln2_b  = (const float*)d_in[9];
    const float* fc1_w  = (const float*)d_in[10];
    const float* fc1_b  = (const float*)d_in[11];
    const float* fc2_w  = (const float*)d_in[12];
    const float* fc2_b  = (const float*)d_in[13];
    float* out = (float*)d_out;
    float* wsf = (float*)d_ws;

    // workspace layout (floats):
    //   [0,        2M)   xn   [64][T]   (reused as xln2)
    //   [2M,      10M)   qkv  [T][192]  (reused as hbuf [256][T])
    //   [10M,     12M)   attn [T][64]
    //   [12M,     14M)   x2   [64][T]
    float* xn   = wsf;
    float* qkv  = wsf + 2097152;
    float* hbuf = qkv;
    float* attn = wsf + 10485760;
    float* x2   = wsf + 12582912;

    k_ln1 <<<128,  256, 0, stream>>>(x, ln1_w, ln1_b, xn);
    k_qkv <<<512,  256, 0, stream>>>(xn, qkv_w, qkv_b, qkv);
    k_attn<<<8192, 256, 0, stream>>>(qkv, rpb, attn);
    k_proj<<<512,  256, 0, stream>>>(attn, proj_w, proj_b, x, x2);
    k_ln2 <<<128,  256, 0, stream>>>(x2, ln2_w, ln2_b, xn);
    k_fc1 <<<1024, 256, 0, stream>>>(xn, fc1_w, fc1_b, hbuf);
    k_fc2 <<<512,  256, 0, stream>>>(hbuf, fc2_w, fc2_b, x2, out);
}

// Round 2
// 307.022 us; speedup vs baseline: 1.0637x; 1.0637x over previous
//
#include <hip/hip_runtime.h>
#include <math.h>

#define TQ   32768    // total tokens N*H*W
#define HWSZ 16384    // H*W
#define CC   64
#define HH   128
#define WW   128
#define C3   192
#define C4   256
#define KS   7

// ---------------- K1: LN1.  x (N,C,H,W) -> xn channel-major [C][T] ----------------
__global__ __launch_bounds__(256) void k_ln1(const float* __restrict__ x,
        const float* __restrict__ w, const float* __restrict__ b,
        float* __restrict__ xn) {
    int t = blockIdx.x * 256 + threadIdx.x;
    int n = t >> 14, hw = t & (HWSZ - 1);
    const float* xr = x + ((size_t)n << 20) + hw;   // n*C*HW
    float s = 0.f, s2 = 0.f;
#pragma unroll
    for (int c = 0; c < CC; ++c) { float v = xr[c * HWSZ]; s += v; s2 += v * v; }
    float m = s * (1.f / 64.f);
    float var = s2 * (1.f / 64.f) - m * m;
    float r = rsqrtf(var + 1e-5f);
#pragma unroll
    for (int c = 0; c < CC; ++c) {
        float v = xr[c * HWSZ];
        xn[(size_t)c * TQ + t] = (v - m) * r * w[c] + b[c];
    }
}

// ---------------- K2: QKV GEMM. xn [C][T] -> qkv token-major [T][192] ----------------
__global__ __launch_bounds__(256) void k_qkv(const float* __restrict__ xn,
        const float* __restrict__ qw, const float* __restrict__ qb,
        float* __restrict__ qkv) {
    __shared__ __align__(16) float w_s[C3 * 65];
    __shared__ __align__(16) float x_s[CC * 68];
    __shared__ float b_s[C3];
    int tid = threadIdx.x;
    int t0 = blockIdx.x * 64;
    for (int i = tid; i < C3 * CC; i += 256) {
        int j = i >> 6, k = i & 63;
        w_s[j * 65 + k] = qw[i];
    }
    if (tid < C3) b_s[tid] = qb[tid];
    {
        int tl = tid & 63, kq = tid >> 6;
        for (int p = 0; p < 16; ++p) {
            int k = p * 4 + kq;
            x_s[k * 68 + tl] = xn[(size_t)k * TQ + t0 + tl];
        }
    }
    __syncthreads();
    int jl = tid & 63, tg = tid >> 6;
    float a0[16], a1[16], a2[16];
#pragma unroll
    for (int i = 0; i < 16; ++i) { a0[i] = 0.f; a1[i] = 0.f; a2[i] = 0.f; }
    for (int k = 0; k < CC; ++k) {
        float w0 = w_s[jl * 65 + k];
        float w1 = w_s[(jl + 64) * 65 + k];
        float w2 = w_s[(jl + 128) * 65 + k];
        const float4* xp = (const float4*)&x_s[k * 68 + tg * 16];
#pragma unroll
        for (int q = 0; q < 4; ++q) {
            float4 xv = xp[q];
            a0[q*4+0] += w0 * xv.x; a0[q*4+1] += w0 * xv.y; a0[q*4+2] += w0 * xv.z; a0[q*4+3] += w0 * xv.w;
            a1[q*4+0] += w1 * xv.x; a1[q*4+1] += w1 * xv.y; a1[q*4+2] += w1 * xv.z; a1[q*4+3] += w1 * xv.w;
            a2[q*4+0] += w2 * xv.x; a2[q*4+1] += w2 * xv.y; a2[q*4+2] += w2 * xv.z; a2[q*4+3] += w2 * xv.w;
        }
    }
    const float qscale = 0.17677669529663687f;  // 1/sqrt(32)
    float bq = b_s[jl], bk = b_s[jl + 64], bv = b_s[jl + 128];
#pragma unroll
    for (int i = 0; i < 16; ++i) {
        size_t t = (size_t)(t0 + tg * 16 + i);
        qkv[t * C3 + jl]        = (a0[i] + bq) * qscale;
        qkv[t * C3 + 64 + jl]   = a1[i] + bk;
        qkv[t * C3 + 128 + jl]  = a2[i] + bv;
    }
}

// ---------------- K3: neighborhood attention, wave = (query, head) ----------------
// QK: lane = neighbor (49 active), per-lane full 32-dim dot (no shuffles).
// softmax: one 6-step butterfly. PV: lane = (half, channel), coalesced v loads.
__global__ __launch_bounds__(256) void k_attn(const float* __restrict__ qkv,
        const float* __restrict__ rpb, float* __restrict__ out) {
    __shared__ float rpb_s[2 * 13 * 13];
    __shared__ __align__(16) float q_s[4][32];
    __shared__ float p_s[4][52];
    int tid = threadIdx.x;
    for (int i = tid; i < 338; i += 256) rpb_s[i] = rpb[i];
    int wv = tid >> 6, lane = tid & 63;
    int wid = blockIdx.x * 4 + wv;       // (query, head) task id
    int qi = wid >> 1, z = wid & 1;
    int n = qi >> 14, hw = qi & (HWSZ - 1);
    int h = hw >> 7, wc = hw & 127;
    int sh = min(max(h - 3, 0), HH - KS);
    int sw = min(max(wc - 3, 0), WW - KS);
    int tbase = n * HWSZ;
    if (lane < 32) q_s[wv][lane] = qkv[(size_t)qi * C3 + z * 32 + lane];
    __syncthreads();

    // ---- QK: lane = neighbor ----
    float s = -1e30f;
    if (lane < 49) {
        int i7 = lane / 7, j7 = lane - i7 * 7;
        int rn = sh + i7, cn = sw + j7;
        int tn = tbase + rn * WW + cn;
        const float4* kp = (const float4*)(qkv + (size_t)tn * C3 + 64 + z * 32);
        const float4* qp = (const float4*)q_s[wv];
        float acc = 0.f;
#pragma unroll
        for (int u = 0; u < 8; ++u) {
            float4 kv = kp[u];
            float4 qv = qp[u];
            acc += qv.x * kv.x + qv.y * kv.y + qv.z * kv.z + qv.w * kv.w;
        }
        s = acc + rpb_s[(z * 13 + (h - rn + 6)) * 13 + (wc - cn + 6)];
    }
    // ---- softmax across 49 lane-resident scores ----
    float mx = s;
    mx = fmaxf(mx, __shfl_xor(mx, 32)); mx = fmaxf(mx, __shfl_xor(mx, 16));
    mx = fmaxf(mx, __shfl_xor(mx, 8));  mx = fmaxf(mx, __shfl_xor(mx, 4));
    mx = fmaxf(mx, __shfl_xor(mx, 2));  mx = fmaxf(mx, __shfl_xor(mx, 1));
    float e = (lane < 49) ? __expf(s - mx) : 0.f;
    float sm = e;
    sm += __shfl_xor(sm, 32); sm += __shfl_xor(sm, 16); sm += __shfl_xor(sm, 8);
    sm += __shfl_xor(sm, 4);  sm += __shfl_xor(sm, 2);  sm += __shfl_xor(sm, 1);
    float inv = 1.f / sm;
    if (lane < 49) p_s[wv][lane] = e * inv;
    __syncthreads();

    // ---- PV: lane = (half, channel); halves split neighbors, combine at end ----
    int d = lane & 31, half = lane >> 5;
    const float* vbase = qkv + 128 + z * 32 + d;
    float acc = 0.f;
    for (int nb = half; nb < 49; nb += 2) {
        int ii = nb / 7, jj = nb - ii * 7;
        int tn = tbase + (sh + ii) * WW + (sw + jj);
        acc += p_s[wv][nb] * vbase[(size_t)tn * C3];
    }
    acc += __shfl_xor(acc, 32);
    if (lane < 32) out[(size_t)qi * CC + z * 32 + d] = acc;
}

// ---------------- K4: proj GEMM + residual. attn [T][64] -> x2 [C][T] ----------------
__global__ __launch_bounds__(256) void k_proj(const float* __restrict__ ain,
        const float* __restrict__ pw, const float* __restrict__ pb,
        const float* __restrict__ x, float* __restrict__ x2) {
    __shared__ __align__(16) float wt_s[CC * 68];
    __shared__ float x_s[CC * 65];
    int tid = threadIdx.x;
    int t0 = blockIdx.x * 64;
    for (int i = tid; i < CC * CC; i += 256) {
        int j = i >> 6, k = i & 63;
        wt_s[k * 68 + j] = pw[i];
    }
    for (int i = tid; i < 64 * 64; i += 256) {
        int tt = i >> 6, c = i & 63;
        x_s[c * 65 + tt] = ain[(size_t)(t0 + tt) * CC + c];
    }
    __syncthreads();
    int tl = tid & 63, jg = tid >> 6;
    float acc[16];
#pragma unroll
    for (int i = 0; i < 16; ++i) acc[i] = 0.f;
    for (int k = 0; k < CC; ++k) {
        float xv = x_s[k * 65 + tl];
        const float4* wp = (const float4*)&wt_s[k * 68 + jg * 16];
#pragma unroll
        for (int q = 0; q < 4; ++q) {
            float4 w4 = wp[q];
            acc[q*4+0] += xv * w4.x; acc[q*4+1] += xv * w4.y;
            acc[q*4+2] += xv * w4.z; acc[q*4+3] += xv * w4.w;
        }
    }
    int t = t0 + tl;
    int n = t >> 14, hw = t & (HWSZ - 1);
#pragma unroll
    for (int jj = 0; jj < 16; ++jj) {
        int j = jg * 16 + jj;
        float resid = x[((size_t)(n * CC + j) << 14) + hw];
        x2[(size_t)j * TQ + t] = acc[jj] + pb[j] + resid;
    }
}

// ---------------- K5: LN2. x2 [C][T] -> xout [C][T] ----------------
__global__ __launch_bounds__(256) void k_ln2(const float* __restrict__ xin,
        const float* __restrict__ w, const float* __restrict__ b,
        float* __restrict__ xout) {
    int t = blockIdx.x * 256 + threadIdx.x;
    float s = 0.f, s2 = 0.f;
#pragma unroll
    for (int c = 0; c < CC; ++c) { float v = xin[(size_t)c * TQ + t]; s += v; s2 += v * v; }
    float m = s * (1.f / 64.f);
    float var = s2 * (1.f / 64.f) - m * m;
    float r = rsqrtf(var + 1e-5f);
#pragma unroll
    for (int c = 0; c < CC; ++c) {
        float v = xin[(size_t)c * TQ + t];
        xout[(size_t)c * TQ + t] = (v - m) * r * w[c] + b[c];
    }
}

// ---------------- K6: FC1 + exact GELU. xln2 [C][T] -> h [C4][T] ----------------
__global__ __launch_bounds__(256) void k_fc1(const float* __restrict__ xin,
        const float* __restrict__ fw, const float* __restrict__ fb,
        float* __restrict__ hbuf) {
    __shared__ __align__(16) float wt_s[CC * 132];
    __shared__ float x_s[CC * 65];
    int tid = threadIdx.x;
    int jb = (blockIdx.x & 1) * 128;
    int t0 = (blockIdx.x >> 1) * 64;
    for (int i = tid; i < 128 * 64; i += 256) {
        int j = i >> 6, k = i & 63;
        wt_s[k * 132 + j] = fw[(size_t)(jb + j) * CC + k];
    }
    int tl = tid & 63, kq = tid >> 6;
    for (int p = 0; p < 16; ++p) {
        int k = p * 4 + kq;
        x_s[k * 65 + tl] = xin[(size_t)k * TQ + t0 + tl];
    }
    __syncthreads();
    int jg = tid >> 6;
    float acc[32];
#pragma unroll
    for (int i = 0; i < 32; ++i) acc[i] = 0.f;
    for (int k = 0; k < CC; ++k) {
        float xv = x_s[k * 65 + tl];
        const float4* wp = (const float4*)&wt_s[k * 132 + jg * 32];
#pragma unroll
        for (int q = 0; q < 8; ++q) {
            float4 w4 = wp[q];
            acc[q*4+0] += xv * w4.x; acc[q*4+1] += xv * w4.y;
            acc[q*4+2] += xv * w4.z; acc[q*4+3] += xv * w4.w;
        }
    }
    int t = t0 + tl;
#pragma unroll
    for (int jj = 0; jj < 32; ++jj) {
        int j = jb + jg * 32 + jj;
        float val = acc[jj] + fb[j];
        float g = 0.5f * val * (1.f + erff(val * 0.70710678118654752f));
        hbuf[(size_t)j * TQ + t] = g;
    }
}

// ---------------- K7: FC2 + residual + NCHW output ----------------
__global__ __launch_bounds__(256) void k_fc2(const float* __restrict__ hbuf,
        const float* __restrict__ fw, const float* __restrict__ fb,
        const float* __restrict__ x2, float* __restrict__ out) {
    __shared__ __align__(16) float wt_s[CC * 68];
    __shared__ float x_s[CC * 65];
    int tid = threadIdx.x;
    int t0 = blockIdx.x * 64;
    int tl = tid & 63, jg = tid >> 6;
    float acc[16];
#pragma unroll
    for (int i = 0; i < 16; ++i) acc[i] = 0.f;
    for (int kb = 0; kb < 4; ++kb) {
        __syncthreads();
        for (int i = tid; i < 64 * 64; i += 256) {
            int j = i >> 6, kl = i & 63;
            wt_s[kl * 68 + j] = fw[(size_t)j * C4 + kb * 64 + kl];
        }
        for (int p = 0; p < 16; ++p) {
            int kl = p * 4 + (tid >> 6);
            x_s[kl * 65 + tl] = hbuf[(size_t)(kb * 64 + kl) * TQ + t0 + tl];
        }
        __syncthreads();
        for (int kl = 0; kl < 64; ++kl) {
            float xv = x_s[kl * 65 + tl];
            const float4* wp = (const float4*)&wt_s[kl * 68 + jg * 16];
#pragma unroll
            for (int q = 0; q < 4; ++q) {
                float4 w4 = wp[q];
                acc[q*4+0] += xv * w4.x; acc[q*4+1] += xv * w4.y;
                acc[q*4+2] += xv * w4.z; acc[q*4+3] += xv * w4.w;
            }
        }
    }
    int t = t0 + tl;
    int n = t >> 14, hw = t & (HWSZ - 1);
#pragma unroll
    for (int jj = 0; jj < 16; ++jj) {
        int j = jg * 16 + jj;
        float val = acc[jj] + fb[j] + x2[(size_t)j * TQ + t];
        out[((size_t)(n * CC + j) << 14) + hw] = val;
    }
}

extern "C" void kernel_launch(void* const* d_in, const int* in_sizes, int n_in,
                              void* d_out, int out_size, void* d_ws, size_t ws_size,
                              hipStream_t stream) {
    const float* x      = (const float*)d_in[0];
    const float* qkv_w  = (const float*)d_in[1];
    const float* qkv_b  = (const float*)d_in[2];
    const float* proj_w = (const float*)d_in[3];
    const float* proj_b = (const float*)d_in[4];
    const float* rpb    = (const float*)d_in[5];
    const float* ln1_w  = (const float*)d_in[6];
    const float* ln1_b  = (const float*)d_in[7];
    const float* ln2_w  = (const float*)d_in[8];
    const float* ln2_b  = (const float*)d_in[9];
    const float* fc1_w  = (const float*)d_in[10];
    const float* fc1_b  = (const float*)d_in[11];
    const float* fc2_w  = (const float*)d_in[12];
    const float* fc2_b  = (const float*)d_in[13];
    float* out = (float*)d_out;
    float* wsf = (float*)d_ws;

    float* xn   = wsf;
    float* qkv  = wsf + 2097152;
    float* hbuf = qkv;
    float* attn = wsf + 10485760;
    float* x2   = wsf + 12582912;

    k_ln1 <<<128,   256, 0, stream>>>(x, ln1_w, ln1_b, xn);
    k_qkv <<<512,   256, 0, stream>>>(xn, qkv_w, qkv_b, qkv);
    k_attn<<<16384, 256, 0, stream>>>(qkv, rpb, attn);
    k_proj<<<512,   256, 0, stream>>>(attn, proj_w, proj_b, x, x2);
    k_ln2 <<<128,   256, 0, stream>>>(x2, ln2_w, ln2_b, xn);
    k_fc1 <<<1024,  256, 0, stream>>>(xn, fc1_w, fc1_b, hbuf);
    k_fc2 <<<512,   256, 0, stream>>>(hbuf, fc2_w, fc2_b, x2, out);
}

// Round 3
// 222.195 us; speedup vs baseline: 1.4698x; 1.3818x over previous
//
#include <hip/hip_runtime.h>
#include <math.h>

#define TQ   32768    // total tokens N*H*W
#define HWSZ 16384    // H*W
#define CC   64
#define HH   128
#define WW   128
#define C3   192
#define C4   256
#define KS   7

typedef _Float16 half2v __attribute__((ext_vector_type(2)));
typedef _Float16 half4v __attribute__((ext_vector_type(4)));
typedef _Float16 half8v __attribute__((ext_vector_type(8)));

// ---------------- K1: LN1.  x (N,C,H,W) -> xn channel-major [C][T] ----------------
__global__ __launch_bounds__(256) void k_ln1(const float* __restrict__ x,
        const float* __restrict__ w, const float* __restrict__ b,
        float* __restrict__ xn) {
    int t = blockIdx.x * 256 + threadIdx.x;
    int n = t >> 14, hw = t & (HWSZ - 1);
    const float* xr = x + ((size_t)n << 20) + hw;   // n*C*HW
    float s = 0.f, s2 = 0.f;
#pragma unroll
    for (int c = 0; c < CC; ++c) { float v = xr[c * HWSZ]; s += v; s2 += v * v; }
    float m = s * (1.f / 64.f);
    float var = s2 * (1.f / 64.f) - m * m;
    float r = rsqrtf(var + 1e-5f);
#pragma unroll
    for (int c = 0; c < CC; ++c) {
        float v = xr[c * HWSZ];
        xn[(size_t)c * TQ + t] = (v - m) * r * w[c] + b[c];
    }
}

// ---------------- K2: QKV GEMM. xn [C][T] -> qkv token-major [T][192] ----------------
__global__ __launch_bounds__(256) void k_qkv(const float* __restrict__ xn,
        const float* __restrict__ qw, const float* __restrict__ qb,
        float* __restrict__ qkv) {
    __shared__ __align__(16) float w_s[C3 * 65];
    __shared__ __align__(16) float x_s[CC * 68];
    __shared__ float b_s[C3];
    int tid = threadIdx.x;
    int t0 = blockIdx.x * 64;
    for (int i = tid; i < C3 * CC; i += 256) {
        int j = i >> 6, k = i & 63;
        w_s[j * 65 + k] = qw[i];
    }
    if (tid < C3) b_s[tid] = qb[tid];
    {
        int tl = tid & 63, kq = tid >> 6;
        for (int p = 0; p < 16; ++p) {
            int k = p * 4 + kq;
            x_s[k * 68 + tl] = xn[(size_t)k * TQ + t0 + tl];
        }
    }
    __syncthreads();
    int jl = tid & 63, tg = tid >> 6;
    float a0[16], a1[16], a2[16];
#pragma unroll
    for (int i = 0; i < 16; ++i) { a0[i] = 0.f; a1[i] = 0.f; a2[i] = 0.f; }
    for (int k = 0; k < CC; ++k) {
        float w0 = w_s[jl * 65 + k];
        float w1 = w_s[(jl + 64) * 65 + k];
        float w2 = w_s[(jl + 128) * 65 + k];
        const float4* xp = (const float4*)&x_s[k * 68 + tg * 16];
#pragma unroll
        for (int q = 0; q < 4; ++q) {
            float4 xv = xp[q];
            a0[q*4+0] += w0 * xv.x; a0[q*4+1] += w0 * xv.y; a0[q*4+2] += w0 * xv.z; a0[q*4+3] += w0 * xv.w;
            a1[q*4+0] += w1 * xv.x; a1[q*4+1] += w1 * xv.y; a1[q*4+2] += w1 * xv.z; a1[q*4+3] += w1 * xv.w;
            a2[q*4+0] += w2 * xv.x; a2[q*4+1] += w2 * xv.y; a2[q*4+2] += w2 * xv.z; a2[q*4+3] += w2 * xv.w;
        }
    }
    const float qscale = 0.17677669529663687f;  // 1/sqrt(32)
    float bq = b_s[jl], bk = b_s[jl + 64], bv = b_s[jl + 128];
#pragma unroll
    for (int i = 0; i < 16; ++i) {
        size_t t = (size_t)(t0 + tg * 16 + i);
        qkv[t * C3 + jl]        = (a0[i] + bq) * qscale;
        qkv[t * C3 + 64 + jl]   = a1[i] + bk;
        qkv[t * C3 + 128 + jl]  = a2[i] + bv;
    }
}

// ---------------- K3: tiled neighborhood attention ----------------
// Block = 8x8 query tile, both heads. 14x14 k/v window staged once to LDS (f16).
// LDS: kv 53.3KB + q 10.2KB + scores 12.8KB + rpb 1.4KB = 77.7KB -> 2 blocks/CU.
#define KV_STRIDE 136   // f16 per window-token row: 64 k + 64 v + 8 pad (16B-aligned, conflict-ideal)
#define QS_STRIDE 80    // f16 per query row (64 ch + pad, 16B-aligned)
#define SS_STRIDE 50

static __device__ inline half2v pk8(half8v a, half8v b, half2v c) {
    c += (half2v){a.s0, a.s1} * (half2v){b.s0, b.s1};
    c += (half2v){a.s2, a.s3} * (half2v){b.s2, b.s3};
    c += (half2v){a.s4, a.s5} * (half2v){b.s4, b.s5};
    c += (half2v){a.s6, a.s7} * (half2v){b.s6, b.s7};
    return c;
}

__global__ __launch_bounds__(256) void k_attn(const float* __restrict__ qkv,
        const float* __restrict__ rpb, float* __restrict__ out) {
    __shared__ __align__(16) _Float16 kv_s[196 * KV_STRIDE]; // [tok][0:64]=k both heads, [64:128]=v
    __shared__ __align__(16) _Float16 q_s[64 * QS_STRIDE];
    __shared__ __align__(16) _Float16 s_s[128 * SS_STRIDE];  // scores -> probs, slot = q*2+z
    __shared__ float rpb_s[338];

    int tid = threadIdx.x;
    int bx = blockIdx.x;
    int n  = bx >> 8;
    int th = (bx >> 4) & 15, tw = bx & 15;
    int h0 = th * 8, w0 = tw * 8;
    int wr0 = min(max(h0 - 3, 0), HH - 14);
    int ww0 = min(max(w0 - 3, 0), WW - 14);
    int tbase = n << 14;

    for (int i = tid; i < 338; i += 256) rpb_s[i] = rpb[i];
    // stage k/v window: 196 tokens x 128 floats (qkv cols 64..191), f32 -> f16
    for (int i = tid; i < 196 * 32; i += 256) {
        int tok = i >> 5, u = i & 31;
        int wi = tok / 14, wj = tok - wi * 14;
        const float4 v4 = *(const float4*)(qkv +
            (size_t)(tbase + (wr0 + wi) * WW + ww0 + wj) * C3 + 64 + u * 4);
        half4v h4 = { (_Float16)v4.x, (_Float16)v4.y, (_Float16)v4.z, (_Float16)v4.w };
        *(half4v*)&kv_s[tok * KV_STRIDE + u * 4] = h4;
    }
    // stage q tile: 64 queries x 64 ch
    for (int i = tid; i < 64 * 16; i += 256) {
        int q = i >> 4, u = i & 15;
        int qg = tbase + (h0 + (q >> 3)) * WW + (w0 + (q & 7));
        const float4 v4 = *(const float4*)(qkv + (size_t)qg * C3 + u * 4);
        half4v h4 = { (_Float16)v4.x, (_Float16)v4.y, (_Float16)v4.z, (_Float16)v4.w };
        *(half4v*)&q_s[q * QS_STRIDE + u * 4] = h4;
    }
    __syncthreads();

    // ---- phase B: scores. thread = (nb-half, head z, query q) ----
    int half_ = tid & 1, z = (tid >> 1) & 1, q = tid >> 2;
    int qy = q >> 3, qx = q & 7;
    int h = h0 + qy, wc = w0 + qx;
    int sh = min(max(h - 3, 0), HH - KS);
    int sw = min(max(wc - 3, 0), WW - KS);
    int oh = sh - wr0, ow = sw - ww0;
    int dhp = h - sh + 6, dwp = wc - sw + 6;
    {
        const half8v* qp = (const half8v*)&q_s[q * QS_STRIDE + z * 32];
        half8v q0 = qp[0], q1 = qp[1], q2 = qp[2], q3 = qp[3];
        int i7 = 0, j7 = half_;
        for (int nb = half_; nb < 49; nb += 2) {
            int tok = (oh + i7) * 14 + (ow + j7);
            const half8v* kp = (const half8v*)&kv_s[tok * KV_STRIDE + z * 32];
            half2v acc2 = { (_Float16)0.f, (_Float16)0.f };
            acc2 = pk8(kp[0], q0, acc2);
            acc2 = pk8(kp[1], q1, acc2);
            acc2 = pk8(kp[2], q2, acc2);
            acc2 = pk8(kp[3], q3, acc2);
            float s = (float)acc2.x + (float)acc2.y
                    + rpb_s[(z * 13 + (dhp - i7)) * 13 + (dwp - j7)];
            s_s[(q * 2 + z) * SS_STRIDE + nb] = (_Float16)s;
            j7 += 2;
            if (j7 >= 7) { j7 -= 7; ++i7; }
        }
    }
    __syncthreads();

    // ---- phase C: softmax, one thread per (q, z) slot ----
    if (tid < 128) {
        _Float16* sp = &s_s[tid * SS_STRIDE];
        float mx = -1e30f;
        for (int i = 0; i < 49; ++i) mx = fmaxf(mx, (float)sp[i]);
        float sum = 0.f;
        for (int i = 0; i < 49; ++i) {
            float e = __expf((float)sp[i] - mx);
            sum += e;
            sp[i] = (_Float16)e;
        }
        float inv = 1.f / sum;
        for (int i = 0; i < 49; ++i) sp[i] = (_Float16)((float)sp[i] * inv);
    }
    __syncthreads();

    // ---- phase D: PV. thread = (16ch-half c16, head z, query q) ----
    {
        int c16 = half_;   // reuse tid&1
        const _Float16* pp = &s_s[(q * 2 + z) * SS_STRIDE];
        half2v acc[8];
#pragma unroll
        for (int j = 0; j < 8; ++j) acc[j] = (half2v){ (_Float16)0.f, (_Float16)0.f };
        int i7 = 0, j7 = 0;
        for (int nb = 0; nb < 49; ++nb) {
            int tok = (oh + i7) * 14 + (ow + j7);
            _Float16 p = pp[nb];
            half2v p2 = { p, p };
            const half8v* vp = (const half8v*)&kv_s[tok * KV_STRIDE + 64 + z * 32 + c16 * 16];
            half8v v0 = vp[0], v1 = vp[1];
            acc[0] += (half2v){v0.s0, v0.s1} * p2;
            acc[1] += (half2v){v0.s2, v0.s3} * p2;
            acc[2] += (half2v){v0.s4, v0.s5} * p2;
            acc[3] += (half2v){v0.s6, v0.s7} * p2;
            acc[4] += (half2v){v1.s0, v1.s1} * p2;
            acc[5] += (half2v){v1.s2, v1.s3} * p2;
            acc[6] += (half2v){v1.s4, v1.s5} * p2;
            acc[7] += (half2v){v1.s6, v1.s7} * p2;
            ++j7;
            if (j7 == 7) { j7 = 0; ++i7; }
        }
        int qg = tbase + h * WW + wc;
        float* op = out + (size_t)qg * CC + z * 32 + c16 * 16;
        float4 o;
        o.x = (float)acc[0].x; o.y = (float)acc[0].y; o.z = (float)acc[1].x; o.w = (float)acc[1].y;
        ((float4*)op)[0] = o;
        o.x = (float)acc[2].x; o.y = (float)acc[2].y; o.z = (float)acc[3].x; o.w = (float)acc[3].y;
        ((float4*)op)[1] = o;
        o.x = (float)acc[4].x; o.y = (float)acc[4].y; o.z = (float)acc[5].x; o.w = (float)acc[5].y;
        ((float4*)op)[2] = o;
        o.x = (float)acc[6].x; o.y = (float)acc[6].y; o.z = (float)acc[7].x; o.w = (float)acc[7].y;
        ((float4*)op)[3] = o;
    }
}

// ---------------- K4: proj GEMM + residual. attn [T][64] -> x2 [C][T] ----------------
__global__ __launch_bounds__(256) void k_proj(const float* __restrict__ ain,
        const float* __restrict__ pw, const float* __restrict__ pb,
        const float* __restrict__ x, float* __restrict__ x2) {
    __shared__ __align__(16) float wt_s[CC * 68];
    __shared__ float x_s[CC * 65];
    int tid = threadIdx.x;
    int t0 = blockIdx.x * 64;
    for (int i = tid; i < CC * CC; i += 256) {
        int j = i >> 6, k = i & 63;
        wt_s[k * 68 + j] = pw[i];
    }
    for (int i = tid; i < 64 * 64; i += 256) {
        int tt = i >> 6, c = i & 63;
        x_s[c * 65 + tt] = ain[(size_t)(t0 + tt) * CC + c];
    }
    __syncthreads();
    int tl = tid & 63, jg = tid >> 6;
    float acc[16];
#pragma unroll
    for (int i = 0; i < 16; ++i) acc[i] = 0.f;
    for (int k = 0; k < CC; ++k) {
        float xv = x_s[k * 65 + tl];
        const float4* wp = (const float4*)&wt_s[k * 68 + jg * 16];
#pragma unroll
        for (int q = 0; q < 4; ++q) {
            float4 w4 = wp[q];
            acc[q*4+0] += xv * w4.x; acc[q*4+1] += xv * w4.y;
            acc[q*4+2] += xv * w4.z; acc[q*4+3] += xv * w4.w;
        }
    }
    int t = t0 + tl;
    int n = t >> 14, hw = t & (HWSZ - 1);
#pragma unroll
    for (int jj = 0; jj < 16; ++jj) {
        int j = jg * 16 + jj;
        float resid = x[((size_t)(n * CC + j) << 14) + hw];
        x2[(size_t)j * TQ + t] = acc[jj] + pb[j] + resid;
    }
}

// ---------------- K5: LN2. x2 [C][T] -> xout [C][T] ----------------
__global__ __launch_bounds__(256) void k_ln2(const float* __restrict__ xin,
        const float* __restrict__ w, const float* __restrict__ b,
        float* __restrict__ xout) {
    int t = blockIdx.x * 256 + threadIdx.x;
    float s = 0.f, s2 = 0.f;
#pragma unroll
    for (int c = 0; c < CC; ++c) { float v = xin[(size_t)c * TQ + t]; s += v; s2 += v * v; }
    float m = s * (1.f / 64.f);
    float var = s2 * (1.f / 64.f) - m * m;
    float r = rsqrtf(var + 1e-5f);
#pragma unroll
    for (int c = 0; c < CC; ++c) {
        float v = xin[(size_t)c * TQ + t];
        xout[(size_t)c * TQ + t] = (v - m) * r * w[c] + b[c];
    }
}

// ---------------- K6: FC1 + exact GELU. xln2 [C][T] -> h [C4][T] ----------------
__global__ __launch_bounds__(256) void k_fc1(const float* __restrict__ xin,
        const float* __restrict__ fw, const float* __restrict__ fb,
        float* __restrict__ hbuf) {
    __shared__ __align__(16) float wt_s[CC * 132];
    __shared__ float x_s[CC * 65];
    int tid = threadIdx.x;
    int jb = (blockIdx.x & 1) * 128;
    int t0 = (blockIdx.x >> 1) * 64;
    for (int i = tid; i < 128 * 64; i += 256) {
        int j = i >> 6, k = i & 63;
        wt_s[k * 132 + j] = fw[(size_t)(jb + j) * CC + k];
    }
    int tl = tid & 63, kq = tid >> 6;
    for (int p = 0; p < 16; ++p) {
        int k = p * 4 + kq;
        x_s[k * 65 + tl] = xin[(size_t)k * TQ + t0 + tl];
    }
    __syncthreads();
    int jg = tid >> 6;
    float acc[32];
#pragma unroll
    for (int i = 0; i < 32; ++i) acc[i] = 0.f;
    for (int k = 0; k < CC; ++k) {
        float xv = x_s[k * 65 + tl];
        const float4* wp = (const float4*)&wt_s[k * 132 + jg * 32];
#pragma unroll
        for (int q = 0; q < 8; ++q) {
            float4 w4 = wp[q];
            acc[q*4+0] += xv * w4.x; acc[q*4+1] += xv * w4.y;
            acc[q*4+2] += xv * w4.z; acc[q*4+3] += xv * w4.w;
        }
    }
    int t = t0 + tl;
#pragma unroll
    for (int jj = 0; jj < 32; ++jj) {
        int j = jb + jg * 32 + jj;
        float val = acc[jj] + fb[j];
        float g = 0.5f * val * (1.f + erff(val * 0.70710678118654752f));
        hbuf[(size_t)j * TQ + t] = g;
    }
}

// ---------------- K7: FC2 + residual + NCHW output ----------------
__global__ __launch_bounds__(256) void k_fc2(const float* __restrict__ hbuf,
        const float* __restrict__ fw, const float* __restrict__ fb,
        const float* __restrict__ x2, float* __restrict__ out) {
    __shared__ __align__(16) float wt_s[CC * 68];
    __shared__ float x_s[CC * 65];
    int tid = threadIdx.x;
    int t0 = blockIdx.x * 64;
    int tl = tid & 63, jg = tid >> 6;
    float acc[16];
#pragma unroll
    for (int i = 0; i < 16; ++i) acc[i] = 0.f;
    for (int kb = 0; kb < 4; ++kb) {
        __syncthreads();
        for (int i = tid; i < 64 * 64; i += 256) {
            int j = i >> 6, kl = i & 63;
            wt_s[kl * 68 + j] = fw[(size_t)j * C4 + kb * 64 + kl];
        }
        for (int p = 0; p < 16; ++p) {
            int kl = p * 4 + (tid >> 6);
            x_s[kl * 65 + tl] = hbuf[(size_t)(kb * 64 + kl) * TQ + t0 + tl];
        }
        __syncthreads();
        for (int kl = 0; kl < 64; ++kl) {
            float xv = x_s[kl * 65 + tl];
            const float4* wp = (const float4*)&wt_s[kl * 68 + jg * 16];
#pragma unroll
            for (int q = 0; q < 4; ++q) {
                float4 w4 = wp[q];
                acc[q*4+0] += xv * w4.x; acc[q*4+1] += xv * w4.y;
                acc[q*4+2] += xv * w4.z; acc[q*4+3] += xv * w4.w;
            }
        }
    }
    int t = t0 + tl;
    int n = t >> 14, hw = t & (HWSZ - 1);
#pragma unroll
    for (int jj = 0; jj < 16; ++jj) {
        int j = jg * 16 + jj;
        float val = acc[jj] + fb[j] + x2[(size_t)j * TQ + t];
        out[((size_t)(n * CC + j) << 14) + hw] = val;
    }
}

extern "C" void kernel_launch(void* const* d_in, const int* in_sizes, int n_in,
                              void* d_out, int out_size, void* d_ws, size_t ws_size,
                              hipStream_t stream) {
    const float* x      = (const float*)d_in[0];
    const float* qkv_w  = (const float*)d_in[1];
    const float* qkv_b  = (const float*)d_in[2];
    const float* proj_w = (const float*)d_in[3];
    const float* proj_b = (const float*)d_in[4];
    const float* rpb    = (const float*)d_in[5];
    const float* ln1_w  = (const float*)d_in[6];
    const float* ln1_b  = (const float*)d_in[7];
    const float* ln2_w  = (const float*)d_in[8];
    const float* ln2_b  = (const float*)d_in[9];
    const float* fc1_w  = (const float*)d_in[10];
    const float* fc1_b  = (const float*)d_in[11];
    const float* fc2_w  = (const float*)d_in[12];
    const float* fc2_b  = (const float*)d_in[13];
    float* out = (float*)d_out;
    float* wsf = (float*)d_ws;

    float* xn   = wsf;
    float* qkv  = wsf + 2097152;
    float* hbuf = qkv;
    float* attn = wsf + 10485760;
    float* x2   = wsf + 12582912;

    k_ln1 <<<128,  256, 0, stream>>>(x, ln1_w, ln1_b, xn);
    k_qkv <<<512,  256, 0, stream>>>(xn, qkv_w, qkv_b, qkv);
    k_attn<<<512,  256, 0, stream>>>(qkv, rpb, attn);
    k_proj<<<512,  256, 0, stream>>>(attn, proj_w, proj_b, x, x2);
    k_ln2 <<<128,  256, 0, stream>>>(x2, ln2_w, ln2_b, xn);
    k_fc1 <<<1024, 256, 0, stream>>>(xn, fc1_w, fc1_b, hbuf);
    k_fc2 <<<512,  256, 0, stream>>>(hbuf, fc2_w, fc2_b, x2, out);
}

// Round 4
// 154.183 us; speedup vs baseline: 2.1181x; 1.4411x over previous
//
#include <hip/hip_runtime.h>
#include <math.h>

#define TQ   32768    // total tokens N*H*W
#define HWSZ 16384    // H*W
#define CC   64
#define HH   128
#define WW   128
#define C3   192
#define C4   256
#define KS   7

typedef _Float16 half2v __attribute__((ext_vector_type(2)));
typedef _Float16 half4v __attribute__((ext_vector_type(4)));
typedef _Float16 half8v __attribute__((ext_vector_type(8)));
typedef float    f32x4  __attribute__((ext_vector_type(4)));

#define MFMA16(a, b, c) __builtin_amdgcn_mfma_f32_16x16x32_f16((a), (b), (c), 0, 0, 0)

// ============ K1: LN1 + layout transform. x NCHW -> xn16 [T][64] f16, x16 [T][64] f16 ============
// 256 tokens/block, thread = token. Stats via coalesced channel-major reads; LDS transpose to
// token-major f16. Pitch 72 f16 (144B, 16B-aligned, bank-balanced for half8 ops).
__global__ __launch_bounds__(256) void k_ln1(const float* __restrict__ x,
        const float* __restrict__ w, const float* __restrict__ b,
        _Float16* __restrict__ xn16, _Float16* __restrict__ x16) {
    __shared__ __align__(16) _Float16 tile[256 * 72];
    __shared__ float w_s[64], b_s[64];
    int tid = threadIdx.x;
    if (tid < 64) { w_s[tid] = w[tid]; b_s[tid] = b[tid]; }
    int t0 = blockIdx.x * 256;
    int t = t0 + tid;
    int n = t >> 14, hw = t & (HWSZ - 1);
    const float* xr = x + ((size_t)n << 20) + hw;
    float s = 0.f, s2 = 0.f;
#pragma unroll
    for (int c = 0; c < CC; ++c) { float v = xr[c * HWSZ]; s += v; s2 += v * v; }
    float m = s * (1.f / 64.f);
    float var = s2 * (1.f / 64.f) - m * m;
    float r = rsqrtf(var + 1e-5f);
    __syncthreads();
    // pass 2: normalized -> LDS (16B chunk writes, bank-balanced)
#pragma unroll
    for (int u = 0; u < 8; ++u) {
        half8v o;
#pragma unroll
        for (int e = 0; e < 8; ++e) {
            int c = u * 8 + e;
            o[e] = (_Float16)((xr[c * HWSZ] - m) * r * w_s[c] + b_s[c]);
        }
        *(half8v*)&tile[tid * 72 + u * 8] = o;
    }
    __syncthreads();
    for (int i = tid; i < 2048; i += 256) {
        int tok = i >> 3, u8 = i & 7;
        *(half8v*)&xn16[(size_t)(t0 + tok) * 64 + u8 * 8] = *(const half8v*)&tile[tok * 72 + u8 * 8];
    }
    __syncthreads();
    // pass 3: raw x -> f16 token-major (for proj residual)
#pragma unroll
    for (int u = 0; u < 8; ++u) {
        half8v o;
#pragma unroll
        for (int e = 0; e < 8; ++e) o[e] = (_Float16)xr[(u * 8 + e) * HWSZ];
        *(half8v*)&tile[tid * 72 + u * 8] = o;
    }
    __syncthreads();
    for (int i = tid; i < 2048; i += 256) {
        int tok = i >> 3, u8 = i & 7;
        *(half8v*)&x16[(size_t)(t0 + tok) * 64 + u8 * 8] = *(const half8v*)&tile[tok * 72 + u8 * 8];
    }
}

// ============ K2: QKV GEMM (MFMA). xn16 [T][64] -> qkv16 [T][192] (q scaled, bias added) ============
// grid 512: bx>>1 = token-block(128), bx&1 = j-col(96). Waves 2x2, wave tile 64t x 48j.
__global__ __launch_bounds__(256) void k_qkv(const _Float16* __restrict__ xn16,
        const float* __restrict__ qw, const float* __restrict__ qb,
        _Float16* __restrict__ qkv16) {
    __shared__ __align__(16) _Float16 A_s[128 * 72];
    __shared__ __align__(16) _Float16 B_s[96 * 72];
    __shared__ float bias_s[96];
    int tid = threadIdx.x;
    int t0 = (blockIdx.x >> 1) * 128;
    int j0 = (blockIdx.x & 1) * 96;
    for (int i = tid; i < 1024; i += 256) {
        int tok = i >> 3, u8 = i & 7;
        *(half8v*)&A_s[tok * 72 + u8 * 8] = *(const half8v*)&xn16[(size_t)(t0 + tok) * 64 + u8 * 8];
    }
    for (int i = tid; i < 1536; i += 256) {
        int jj = i >> 4, seg = i & 15;
        float4 v4 = *(const float4*)&qw[(size_t)(j0 + jj) * 64 + seg * 4];
        half4v h4 = { (_Float16)v4.x, (_Float16)v4.y, (_Float16)v4.z, (_Float16)v4.w };
        *(half4v*)&B_s[jj * 72 + seg * 4] = h4;
    }
    if (tid < 96) bias_s[tid] = qb[j0 + tid];
    __syncthreads();
    int lane = tid & 63, wv = tid >> 6;
    int quad = lane >> 4, l16 = lane & 15;
    int mt0 = (wv & 1) * 64, nt0 = (wv >> 1) * 48;
    f32x4 acc[4][3];
#pragma unroll
    for (int mf = 0; mf < 4; ++mf)
#pragma unroll
        for (int nf = 0; nf < 3; ++nf) acc[mf][nf] = (f32x4){0.f, 0.f, 0.f, 0.f};
#pragma unroll
    for (int ks = 0; ks < 64; ks += 32) {
        half8v a[4], bfr[3];
#pragma unroll
        for (int mf = 0; mf < 4; ++mf)
            a[mf] = *(const half8v*)&A_s[(mt0 + mf * 16 + l16) * 72 + ks + quad * 8];
#pragma unroll
        for (int nf = 0; nf < 3; ++nf)
            bfr[nf] = *(const half8v*)&B_s[(nt0 + nf * 16 + l16) * 72 + ks + quad * 8];
#pragma unroll
        for (int mf = 0; mf < 4; ++mf)
#pragma unroll
            for (int nf = 0; nf < 3; ++nf) acc[mf][nf] = MFMA16(a[mf], bfr[nf], acc[mf][nf]);
    }
    const float qscale = 0.17677669529663687f;
#pragma unroll
    for (int mf = 0; mf < 4; ++mf)
#pragma unroll
        for (int nf = 0; nf < 3; ++nf) {
            int j = j0 + nt0 + nf * 16 + l16;
            float bias = bias_s[nt0 + nf * 16 + l16];
            float sc = (j < 64) ? qscale : 1.f;
#pragma unroll
            for (int r = 0; r < 4; ++r) {
                int t = t0 + mt0 + mf * 16 + quad * 4 + r;
                qkv16[(size_t)t * C3 + j] = (_Float16)((acc[mf][nf][r] + bias) * sc);
            }
        }
}

// ============ K3: tiled neighborhood attention (f16 in/out) ============
#define KV_STRIDE 136
#define QS_STRIDE 80
#define SS_STRIDE 50

static __device__ inline half2v pk8(half8v a, half8v b, half2v c) {
    c += (half2v){a.s0, a.s1} * (half2v){b.s0, b.s1};
    c += (half2v){a.s2, a.s3} * (half2v){b.s2, b.s3};
    c += (half2v){a.s4, a.s5} * (half2v){b.s4, b.s5};
    c += (half2v){a.s6, a.s7} * (half2v){b.s6, b.s7};
    return c;
}

__global__ __launch_bounds__(256) void k_attn(const _Float16* __restrict__ qkv16,
        const float* __restrict__ rpb, _Float16* __restrict__ out) {
    __shared__ __align__(16) _Float16 kv_s[196 * KV_STRIDE];
    __shared__ __align__(16) _Float16 q_s[64 * QS_STRIDE];
    __shared__ __align__(16) _Float16 s_s[128 * SS_STRIDE];
    __shared__ float rpb_s[338];

    int tid = threadIdx.x;
    int bx = blockIdx.x;
    int n  = bx >> 8;
    int th = (bx >> 4) & 15, tw = bx & 15;
    int h0 = th * 8, w0 = tw * 8;
    int wr0 = min(max(h0 - 3, 0), HH - 14);
    int ww0 = min(max(w0 - 3, 0), WW - 14);
    int tbase = n << 14;

    for (int i = tid; i < 338; i += 256) rpb_s[i] = rpb[i];
    for (int i = tid; i < 196 * 16; i += 256) {
        int tok = i >> 4, u = i & 15;
        int wi = tok / 14, wj = tok - wi * 14;
        *(half8v*)&kv_s[tok * KV_STRIDE + u * 8] = *(const half8v*)&qkv16[
            (size_t)(tbase + (wr0 + wi) * WW + ww0 + wj) * C3 + 64 + u * 8];
    }
    for (int i = tid; i < 64 * 8; i += 256) {
        int q = i >> 3, u = i & 7;
        int qg = tbase + (h0 + (q >> 3)) * WW + (w0 + (q & 7));
        *(half8v*)&q_s[q * QS_STRIDE + u * 8] = *(const half8v*)&qkv16[(size_t)qg * C3 + u * 8];
    }
    __syncthreads();

    int half_ = tid & 1, z = (tid >> 1) & 1, q = tid >> 2;
    int qy = q >> 3, qx = q & 7;
    int h = h0 + qy, wc = w0 + qx;
    int sh = min(max(h - 3, 0), HH - KS);
    int sw = min(max(wc - 3, 0), WW - KS);
    int oh = sh - wr0, ow = sw - ww0;
    int dhp = h - sh + 6, dwp = wc - sw + 6;
    {
        const half8v* qp = (const half8v*)&q_s[q * QS_STRIDE + z * 32];
        half8v q0 = qp[0], q1 = qp[1], q2 = qp[2], q3 = qp[3];
        int i7 = 0, j7 = half_;
        for (int nb = half_; nb < 49; nb += 2) {
            int tok = (oh + i7) * 14 + (ow + j7);
            const half8v* kp = (const half8v*)&kv_s[tok * KV_STRIDE + z * 32];
            half2v acc2 = { (_Float16)0.f, (_Float16)0.f };
            acc2 = pk8(kp[0], q0, acc2);
            acc2 = pk8(kp[1], q1, acc2);
            acc2 = pk8(kp[2], q2, acc2);
            acc2 = pk8(kp[3], q3, acc2);
            float s = (float)acc2.x + (float)acc2.y
                    + rpb_s[(z * 13 + (dhp - i7)) * 13 + (dwp - j7)];
            s_s[(q * 2 + z) * SS_STRIDE + nb] = (_Float16)s;
            j7 += 2;
            if (j7 >= 7) { j7 -= 7; ++i7; }
        }
    }
    __syncthreads();

    if (tid < 128) {
        _Float16* sp = &s_s[tid * SS_STRIDE];
        float mx = -1e30f;
        for (int i = 0; i < 49; ++i) mx = fmaxf(mx, (float)sp[i]);
        float sum = 0.f;
        for (int i = 0; i < 49; ++i) {
            float e = __expf((float)sp[i] - mx);
            sum += e;
            sp[i] = (_Float16)e;
        }
        float inv = 1.f / sum;
        for (int i = 0; i < 49; ++i) sp[i] = (_Float16)((float)sp[i] * inv);
    }
    __syncthreads();

    {
        int c16 = half_;
        const _Float16* pp = &s_s[(q * 2 + z) * SS_STRIDE];
        half2v acc[8];
#pragma unroll
        for (int j = 0; j < 8; ++j) acc[j] = (half2v){ (_Float16)0.f, (_Float16)0.f };
        int i7 = 0, j7 = 0;
        for (int nb = 0; nb < 49; ++nb) {
            int tok = (oh + i7) * 14 + (ow + j7);
            _Float16 p = pp[nb];
            half2v p2 = { p, p };
            const half8v* vp = (const half8v*)&kv_s[tok * KV_STRIDE + 64 + z * 32 + c16 * 16];
            half8v v0 = vp[0], v1 = vp[1];
            acc[0] += (half2v){v0.s0, v0.s1} * p2;
            acc[1] += (half2v){v0.s2, v0.s3} * p2;
            acc[2] += (half2v){v0.s4, v0.s5} * p2;
            acc[3] += (half2v){v0.s6, v0.s7} * p2;
            acc[4] += (half2v){v1.s0, v1.s1} * p2;
            acc[5] += (half2v){v1.s2, v1.s3} * p2;
            acc[6] += (half2v){v1.s4, v1.s5} * p2;
            acc[7] += (half2v){v1.s6, v1.s7} * p2;
            ++j7;
            if (j7 == 7) { j7 = 0; ++i7; }
        }
        int qg = tbase + h * WW + wc;
        _Float16* op = out + (size_t)qg * CC + z * 32 + c16 * 16;
        half8v o0 = {acc[0].x, acc[0].y, acc[1].x, acc[1].y, acc[2].x, acc[2].y, acc[3].x, acc[3].y};
        half8v o1 = {acc[4].x, acc[4].y, acc[5].x, acc[5].y, acc[6].x, acc[6].y, acc[7].x, acc[7].y};
        *(half8v*)op = o0;
        *(half8v*)(op + 8) = o1;
    }
}

// ============ K4: proj GEMM (MFMA) + residual. attn16 [T][64] + x16 -> x2_16 [T][64] ============
// grid 256 token-blocks(128). Waves 4x1, wave tile 32t x 64j.
__global__ __launch_bounds__(256) void k_proj(const _Float16* __restrict__ ain,
        const float* __restrict__ pw, const float* __restrict__ pb,
        const _Float16* __restrict__ x16, _Float16* __restrict__ x2_16) {
    __shared__ __align__(16) _Float16 A_s[128 * 72];
    __shared__ __align__(16) _Float16 B_s[64 * 72];
    __shared__ float bias_s[64];
    int tid = threadIdx.x;
    int t0 = blockIdx.x * 128;
    for (int i = tid; i < 1024; i += 256) {
        int tok = i >> 3, u8 = i & 7;
        *(half8v*)&A_s[tok * 72 + u8 * 8] = *(const half8v*)&ain[(size_t)(t0 + tok) * 64 + u8 * 8];
    }
    for (int i = tid; i < 1024; i += 256) {
        int jj = i >> 4, seg = i & 15;
        float4 v4 = *(const float4*)&pw[(size_t)jj * 64 + seg * 4];
        half4v h4 = { (_Float16)v4.x, (_Float16)v4.y, (_Float16)v4.z, (_Float16)v4.w };
        *(half4v*)&B_s[jj * 72 + seg * 4] = h4;
    }
    if (tid < 64) bias_s[tid] = pb[tid];
    __syncthreads();
    int lane = tid & 63, wv = tid >> 6;
    int quad = lane >> 4, l16 = lane & 15;
    int mt0 = wv * 32;
    f32x4 acc[2][4];
#pragma unroll
    for (int mf = 0; mf < 2; ++mf)
#pragma unroll
        for (int nf = 0; nf < 4; ++nf) acc[mf][nf] = (f32x4){0.f, 0.f, 0.f, 0.f};
#pragma unroll
    for (int ks = 0; ks < 64; ks += 32) {
        half8v a[2], bfr[4];
#pragma unroll
        for (int mf = 0; mf < 2; ++mf)
            a[mf] = *(const half8v*)&A_s[(mt0 + mf * 16 + l16) * 72 + ks + quad * 8];
#pragma unroll
        for (int nf = 0; nf < 4; ++nf)
            bfr[nf] = *(const half8v*)&B_s[(nf * 16 + l16) * 72 + ks + quad * 8];
#pragma unroll
        for (int mf = 0; mf < 2; ++mf)
#pragma unroll
            for (int nf = 0; nf < 4; ++nf) acc[mf][nf] = MFMA16(a[mf], bfr[nf], acc[mf][nf]);
    }
#pragma unroll
    for (int mf = 0; mf < 2; ++mf)
#pragma unroll
        for (int nf = 0; nf < 4; ++nf) {
            int j = nf * 16 + l16;
            float bias = bias_s[j];
#pragma unroll
            for (int r = 0; r < 4; ++r) {
                int t = t0 + mt0 + mf * 16 + quad * 4 + r;
                float v = acc[mf][nf][r] + bias + (float)x16[(size_t)t * 64 + j];
                x2_16[(size_t)t * 64 + j] = (_Float16)v;
            }
        }
}

// ============ K5: LN2. x2_16 [T][64] -> xn2_16 [T][64] (thread = token) ============
__global__ __launch_bounds__(256) void k_ln2(const _Float16* __restrict__ xin,
        const float* __restrict__ w, const float* __restrict__ b,
        _Float16* __restrict__ xout) {
    __shared__ float w_s[64], b_s[64];
    int tid = threadIdx.x;
    if (tid < 64) { w_s[tid] = w[tid]; b_s[tid] = b[tid]; }
    __syncthreads();
    int t = blockIdx.x * 256 + tid;
    half8v hv[8];
#pragma unroll
    for (int u = 0; u < 8; ++u) hv[u] = *(const half8v*)&xin[(size_t)t * 64 + u * 8];
    float s = 0.f, s2 = 0.f;
#pragma unroll
    for (int u = 0; u < 8; ++u)
#pragma unroll
        for (int e = 0; e < 8; ++e) { float f = (float)hv[u][e]; s += f; s2 += f * f; }
    float m = s * (1.f / 64.f);
    float var = s2 * (1.f / 64.f) - m * m;
    float r = rsqrtf(var + 1e-5f);
#pragma unroll
    for (int u = 0; u < 8; ++u) {
        half8v o;
#pragma unroll
        for (int e = 0; e < 8; ++e) {
            int c = u * 8 + e;
            o[e] = (_Float16)(((float)hv[u][e] - m) * r * w_s[c] + b_s[c]);
        }
        *(half8v*)&xout[(size_t)t * 64 + u * 8] = o;
    }
}

// ============ K6: FC1 GEMM (MFMA) + exact GELU. xn2_16 [T][64] -> hbuf16 [T][256] ============
// grid 512: bx>>1 = token-block(128), bx&1 = j-col(128). Waves 2x2, wave tile 64t x 64j.
__global__ __launch_bounds__(256) void k_fc1(const _Float16* __restrict__ xin,
        const float* __restrict__ fw, const float* __restrict__ fb,
        _Float16* __restrict__ hbuf16) {
    __shared__ __align__(16) _Float16 A_s[128 * 72];
    __shared__ __align__(16) _Float16 B_s[128 * 72];
    __shared__ float bias_s[128];
    int tid = threadIdx.x;
    int t0 = (blockIdx.x >> 1) * 128;
    int j0 = (blockIdx.x & 1) * 128;
    for (int i = tid; i < 1024; i += 256) {
        int tok = i >> 3, u8 = i & 7;
        *(half8v*)&A_s[tok * 72 + u8 * 8] = *(const half8v*)&xin[(size_t)(t0 + tok) * 64 + u8 * 8];
    }
    for (int i = tid; i < 2048; i += 256) {
        int jj = i >> 4, seg = i & 15;
        float4 v4 = *(const float4*)&fw[(size_t)(j0 + jj) * 64 + seg * 4];
        half4v h4 = { (_Float16)v4.x, (_Float16)v4.y, (_Float16)v4.z, (_Float16)v4.w };
        *(half4v*)&B_s[jj * 72 + seg * 4] = h4;
    }
    if (tid < 128) bias_s[tid] = fb[j0 + tid];
    __syncthreads();
    int lane = tid & 63, wv = tid >> 6;
    int quad = lane >> 4, l16 = lane & 15;
    int mt0 = (wv & 1) * 64, nt0 = (wv >> 1) * 64;
    f32x4 acc[4][4];
#pragma unroll
    for (int mf = 0; mf < 4; ++mf)
#pragma unroll
        for (int nf = 0; nf < 4; ++nf) acc[mf][nf] = (f32x4){0.f, 0.f, 0.f, 0.f};
#pragma unroll
    for (int ks = 0; ks < 64; ks += 32) {
        half8v a[4], bfr[4];
#pragma unroll
        for (int mf = 0; mf < 4; ++mf)
            a[mf] = *(const half8v*)&A_s[(mt0 + mf * 16 + l16) * 72 + ks + quad * 8];
#pragma unroll
        for (int nf = 0; nf < 4; ++nf)
            bfr[nf] = *(const half8v*)&B_s[(nt0 + nf * 16 + l16) * 72 + ks + quad * 8];
#pragma unroll
        for (int mf = 0; mf < 4; ++mf)
#pragma unroll
            for (int nf = 0; nf < 4; ++nf) acc[mf][nf] = MFMA16(a[mf], bfr[nf], acc[mf][nf]);
    }
#pragma unroll
    for (int mf = 0; mf < 4; ++mf)
#pragma unroll
        for (int nf = 0; nf < 4; ++nf) {
            int j = j0 + nt0 + nf * 16 + l16;
            float bias = bias_s[nt0 + nf * 16 + l16];
#pragma unroll
            for (int r = 0; r < 4; ++r) {
                int t = t0 + mt0 + mf * 16 + quad * 4 + r;
                float v = acc[mf][nf][r] + bias;
                float g = 0.5f * v * (1.f + erff(v * 0.70710678118654752f));
                hbuf16[(size_t)t * C4 + j] = (_Float16)g;
            }
        }
}

// ============ K7: FC2 GEMM (MFMA, K=256) + residual + NCHW f32 out via LDS transpose ============
// grid 256 token-blocks(128). Waves 4x1, wave tile 32t x 64j, 4 K-panels of 64.
__global__ __launch_bounds__(256) void k_fc2(const _Float16* __restrict__ hbuf16,
        const float* __restrict__ fw, const float* __restrict__ fb,
        const _Float16* __restrict__ x2_16, float* __restrict__ out) {
    __shared__ union {
        struct { __align__(16) _Float16 A[128 * 72]; __align__(16) _Float16 B[64 * 72]; } st;
        float tr[64 * 132];
    } u;
    __shared__ float fb_s[64];
    int tid = threadIdx.x;
    int t0 = blockIdx.x * 128;
    int lane = tid & 63, wv = tid >> 6;
    int quad = lane >> 4, l16 = lane & 15;
    int mt0 = wv * 32;
    if (tid < 64) fb_s[tid] = fb[tid];
    f32x4 acc[2][4];
#pragma unroll
    for (int mf = 0; mf < 2; ++mf)
#pragma unroll
        for (int nf = 0; nf < 4; ++nf) acc[mf][nf] = (f32x4){0.f, 0.f, 0.f, 0.f};
    for (int kp = 0; kp < 4; ++kp) {
        if (kp) __syncthreads();
        for (int i = tid; i < 1024; i += 256) {
            int tok = i >> 3, u8 = i & 7;
            *(half8v*)&u.st.A[tok * 72 + u8 * 8] =
                *(const half8v*)&hbuf16[(size_t)(t0 + tok) * C4 + kp * 64 + u8 * 8];
        }
        for (int i = tid; i < 1024; i += 256) {
            int jj = i >> 4, seg = i & 15;
            float4 v4 = *(const float4*)&fw[(size_t)jj * C4 + kp * 64 + seg * 4];
            half4v h4 = { (_Float16)v4.x, (_Float16)v4.y, (_Float16)v4.z, (_Float16)v4.w };
            *(half4v*)&u.st.B[jj * 72 + seg * 4] = h4;
        }
        __syncthreads();
#pragma unroll
        for (int ks = 0; ks < 64; ks += 32) {
            half8v a[2], bfr[4];
#pragma unroll
            for (int mf = 0; mf < 2; ++mf)
                a[mf] = *(const half8v*)&u.st.A[(mt0 + mf * 16 + l16) * 72 + ks + quad * 8];
#pragma unroll
            for (int nf = 0; nf < 4; ++nf)
                bfr[nf] = *(const half8v*)&u.st.B[(nf * 16 + l16) * 72 + ks + quad * 8];
#pragma unroll
            for (int mf = 0; mf < 2; ++mf)
#pragma unroll
                for (int nf = 0; nf < 4; ++nf) acc[mf][nf] = MFMA16(a[mf], bfr[nf], acc[mf][nf]);
        }
    }
    __syncthreads();
    // epilogue: bias + residual, write transposed tile [j][t]
#pragma unroll
    for (int mf = 0; mf < 2; ++mf)
#pragma unroll
        for (int nf = 0; nf < 4; ++nf) {
            int j = nf * 16 + l16;
            float bias = fb_s[j];
#pragma unroll
            for (int r = 0; r < 4; ++r) {
                int tl = mt0 + mf * 16 + quad * 4 + r;
                float v = acc[mf][nf][r] + bias + (float)x2_16[(size_t)(t0 + tl) * 64 + j];
                u.tr[j * 132 + tl] = v;
            }
        }
    __syncthreads();
    int n = t0 >> 14, hw0 = t0 & (HWSZ - 1);
    for (int i = tid; i < 64 * 32; i += 256) {
        int j = i >> 5, seg = i & 31;
        float4 v = *(const float4*)&u.tr[j * 132 + seg * 4];
        *(float4*)&out[((size_t)(n * CC + j) << 14) + hw0 + seg * 4] = v;
    }
}

extern "C" void kernel_launch(void* const* d_in, const int* in_sizes, int n_in,
                              void* d_out, int out_size, void* d_ws, size_t ws_size,
                              hipStream_t stream) {
    const float* x      = (const float*)d_in[0];
    const float* qkv_w  = (const float*)d_in[1];
    const float* qkv_b  = (const float*)d_in[2];
    const float* proj_w = (const float*)d_in[3];
    const float* proj_b = (const float*)d_in[4];
    const float* rpb    = (const float*)d_in[5];
    const float* ln1_w  = (const float*)d_in[6];
    const float* ln1_b  = (const float*)d_in[7];
    const float* ln2_w  = (const float*)d_in[8];
    const float* ln2_b  = (const float*)d_in[9];
    const float* fc1_w  = (const float*)d_in[10];
    const float* fc1_b  = (const float*)d_in[11];
    const float* fc2_w  = (const float*)d_in[12];
    const float* fc2_b  = (const float*)d_in[13];
    float* out = (float*)d_out;
    char* ws = (char*)d_ws;

    // f16 workspace layout (bytes):
    _Float16* xn16   = (_Float16*)(ws);                 //  4.19 MB [T][64]
    _Float16* x16    = (_Float16*)(ws + 4194304);       //  4.19 MB [T][64]
    _Float16* qkv16  = (_Float16*)(ws + 8388608);       // 12.58 MB [T][192]
    _Float16* attn16 = (_Float16*)(ws + 20971520);      //  4.19 MB [T][64]
    _Float16* x2_16  = (_Float16*)(ws + 25165824);      //  4.19 MB [T][64]
    _Float16* xn2_16 = (_Float16*)(ws + 29360128);      //  4.19 MB [T][64]
    _Float16* hbuf16 = (_Float16*)(ws + 33554432);      // 16.78 MB [T][256]

    k_ln1 <<<128, 256, 0, stream>>>(x, ln1_w, ln1_b, xn16, x16);
    k_qkv <<<512, 256, 0, stream>>>(xn16, qkv_w, qkv_b, qkv16);
    k_attn<<<512, 256, 0, stream>>>(qkv16, rpb, attn16);
    k_proj<<<256, 256, 0, stream>>>(attn16, proj_w, proj_b, x16, x2_16);
    k_ln2 <<<128, 256, 0, stream>>>(x2_16, ln2_w, ln2_b, xn2_16);
    k_fc1 <<<512, 256, 0, stream>>>(xn2_16, fc1_w, fc1_b, hbuf16);
    k_fc2 <<<256, 256, 0, stream>>>(hbuf16, fc2_w, fc2_b, x2_16, out);
}